// Round 4
// baseline (764.756 us; speedup 1.0000x reference)
//
#include <hip/hip_runtime.h>
#include <hip/hip_bf16.h>

typedef __attribute__((ext_vector_type(8))) short short8;
typedef __attribute__((ext_vector_type(4))) short sv4;
typedef __attribute__((ext_vector_type(4))) float floatx4;

#define N_CELLS  500000
#define B_SAMP   512
#define D_X      128
#define D_Z      32
#define D_IN     160
#define H_DIM    256
#define D_OUT    16

#define M_TILE   32
#define N_TILES  (N_CELLS / M_TILE)   // 15625
#define GRID     256
#define LDA      168   // sXp leading dim (bf16): 336 B row stride, 16B-aligned
#define LDH      264   // sH leading dim (bf16): 528 B row stride, 16B-aligned

// workspace layout (bytes)
#define OFF_W1P   0           // 16*5*64*8*2   = 81920
#define OFF_W2P   81920       // 16*8*64*8*2   = 131072
#define OFF_W3P   212992      // 1*8*64*8*2    = 8192
#define OFF_PART  221184      // 256 * 8704 * 4 = 8912896   (~9.1 MB total)
#define PART_STRIDE 8704      // 8192 sums + 512 counts

// Repack W[K][N] fp32 -> bf16 fragments. Under the A<->B transpose the same
// layout serves as A-frags for A=W^T: frag[((t*kS+s)*64+L)*8+j] =
// W[s*32+(L>>4)*8+j][t*16+(L&15)]  (lane L: m=L&15 (col of W), k=(L>>4)*8+j).
__global__ void pack_w(const float* __restrict__ W, __hip_bfloat16* __restrict__ dst,
                       int N, int kS) {
    int idx = blockIdx.x * blockDim.x + threadIdx.x;
    int j = idx & 7;
    int L = (idx >> 3) & 63;
    int s = (idx >> 9) % kS;
    int t = idx / (kS << 9);
    int k = s * 32 + ((L >> 4) << 3) + j;
    int n = t * 16 + (L & 15);
    dst[idx] = __float2bfloat16(W[(size_t)k * N + n]);
}

static __device__ __forceinline__ short f2bf(float f) {
    __hip_bfloat16 h = __float2bfloat16(f);
    return *(short*)&h;
}

__global__ __launch_bounds__(512, 2)
void fused_persist(const float* __restrict__ X, const float* __restrict__ Z,
                   const int* __restrict__ c2b, const int* __restrict__ sidx,
                   const float* __restrict__ b1, const float* __restrict__ b2,
                   const __hip_bfloat16* __restrict__ w1p,
                   const __hip_bfloat16* __restrict__ w2p,
                   const __hip_bfloat16* __restrict__ w3p,
                   float* __restrict__ part) {
    __shared__ __hip_bfloat16 sXp[M_TILE][LDA];      // 10752 B
    __shared__ __hip_bfloat16 sH[2][M_TILE][LDH];    // 33792 B
    __shared__ float lAcc[B_SAMP * D_OUT];           // 32768 B
    __shared__ float lCnt[B_SAMP];                   // 2048 B
    __shared__ int   sSeg[M_TILE];

    const int tid = threadIdx.x;
    const int w   = tid >> 6;     // wave 0..7, owns H-cols [32w, 32w+32)
    const int L   = tid & 63;
    const int q   = L >> 4;
    const int ln  = L & 15;

    // ---- zero block-local accumulators ----
    for (int i = tid; i < B_SAMP * D_OUT; i += 512) lAcc[i] = 0.f;
    for (int i = tid; i < B_SAMP; i += 512) lCnt[i] = 0.f;

    // ---- load weight fragments into registers (once per block) ----
    short8 W1A[2][5], W2A[2][8], W3A;
#pragma unroll
    for (int nt = 0; nt < 2; ++nt)
#pragma unroll
        for (int s = 0; s < 5; ++s)
            W1A[nt][s] = *(const short8*)(w1p + (size_t)((((2 * w + nt) * 5 + s) << 6) + L) * 8);
#pragma unroll
    for (int nt = 0; nt < 2; ++nt)
#pragma unroll
        for (int s = 0; s < 8; ++s)
            W2A[nt][s] = *(const short8*)(w2p + (size_t)((((2 * w + nt) * 8 + s) << 6) + L) * 8);
    W3A = *(const short8*)(w3p + (size_t)((w << 6) + L) * 8);

    float4 bias1[2], bias2[2];
#pragma unroll
    for (int nt = 0; nt < 2; ++nt) {
        bias1[nt] = *(const float4*)&b1[w * 32 + nt * 16 + q * 4];
        bias2[nt] = *(const float4*)&b2[w * 32 + nt * 16 + q * 4];
    }
    __syncthreads();

    // ---- prefetch registers for first tile ----
    const int rowx = tid >> 4, colx = (tid & 15) * 8;   // X: 32 rows x 128 cols
    const int rowz = (tid >> 3) & 31, colz = (tid & 7) * 4;
    float4 xv0, xv1, zv;
    int cb = 0;
    {
        int base = blockIdx.x * M_TILE;
        const float* xr = X + (size_t)(base + rowx) * D_X + colx;
        xv0 = *(const float4*)xr;
        xv1 = *(const float4*)(xr + 4);
        cb  = c2b[base + rowz];
        if (tid < 256) zv = *(const float4*)(Z + (size_t)cb * D_Z + colz);
    }

    for (int tt = blockIdx.x; tt < N_TILES; tt += GRID) {
        // ---- stage from prefetch regs: log1p(X)|Z as bf16, seg ids, counts ----
        {
            short8 pk;
            pk[0] = f2bf(__logf(1.0f + xv0.x)); pk[1] = f2bf(__logf(1.0f + xv0.y));
            pk[2] = f2bf(__logf(1.0f + xv0.z)); pk[3] = f2bf(__logf(1.0f + xv0.w));
            pk[4] = f2bf(__logf(1.0f + xv1.x)); pk[5] = f2bf(__logf(1.0f + xv1.y));
            pk[6] = f2bf(__logf(1.0f + xv1.z)); pk[7] = f2bf(__logf(1.0f + xv1.w));
            *(short8*)&sXp[rowx][colx] = pk;
            if (tid < 256) {
                sv4 zp;
                zp[0] = f2bf(zv.x); zp[1] = f2bf(zv.y);
                zp[2] = f2bf(zv.z); zp[3] = f2bf(zv.w);
                *(sv4*)&sXp[rowz][D_X + colz] = zp;
                if ((tid & 7) == 0) {
                    int s = sidx[cb];
                    sSeg[rowz] = s;
                    atomicAdd(&lCnt[s], 1.0f);
                }
            }
        }
        __syncthreads();

        // ---- prefetch next tile (hidden under GEMMs) ----
        {
            int tn = tt + GRID;
            if (tn < N_TILES) {
                int nb = tn * M_TILE;
                const float* xr = X + (size_t)(nb + rowx) * D_X + colx;
                xv0 = *(const float4*)xr;
                xv1 = *(const float4*)(xr + 4);
                cb  = c2b[nb + rowz];
                if (tid < 256) zv = *(const float4*)(Z + (size_t)cb * D_Z + colz);
            }
        }

        // ---- GEMM1: D = W1^T · Xp^T  (rows=H-cols, cols=cells) ----
        floatx4 acc[2][2];
#pragma unroll
        for (int nt = 0; nt < 2; ++nt)
#pragma unroll
            for (int ct = 0; ct < 2; ++ct)
                acc[nt][ct] = (floatx4){0.f, 0.f, 0.f, 0.f};
#pragma unroll
        for (int s = 0; s < 5; ++s) {
            short8 x0 = *(const short8*)&sXp[ln][s * 32 + q * 8];
            short8 x1 = *(const short8*)&sXp[16 + ln][s * 32 + q * 8];
#pragma unroll
            for (int nt = 0; nt < 2; ++nt) {
                acc[nt][0] = __builtin_amdgcn_mfma_f32_16x16x32_bf16(W1A[nt][s], x0, acc[nt][0], 0, 0, 0);
                acc[nt][1] = __builtin_amdgcn_mfma_f32_16x16x32_bf16(W1A[nt][s], x1, acc[nt][1], 0, 0, 0);
            }
        }
#pragma unroll
        for (int nt = 0; nt < 2; ++nt)
#pragma unroll
            for (int ct = 0; ct < 2; ++ct) {
                sv4 pk;
                pk[0] = f2bf(fmaxf(acc[nt][ct][0] + bias1[nt].x, 0.f));
                pk[1] = f2bf(fmaxf(acc[nt][ct][1] + bias1[nt].y, 0.f));
                pk[2] = f2bf(fmaxf(acc[nt][ct][2] + bias1[nt].z, 0.f));
                pk[3] = f2bf(fmaxf(acc[nt][ct][3] + bias1[nt].w, 0.f));
                *(sv4*)&sH[0][ct * 16 + ln][w * 32 + nt * 16 + q * 4] = pk;
            }
        __syncthreads();

        // ---- GEMM2 ----
#pragma unroll
        for (int nt = 0; nt < 2; ++nt)
#pragma unroll
            for (int ct = 0; ct < 2; ++ct)
                acc[nt][ct] = (floatx4){0.f, 0.f, 0.f, 0.f};
#pragma unroll
        for (int s = 0; s < 8; ++s) {
            short8 x0 = *(const short8*)&sH[0][ln][s * 32 + q * 8];
            short8 x1 = *(const short8*)&sH[0][16 + ln][s * 32 + q * 8];
#pragma unroll
            for (int nt = 0; nt < 2; ++nt) {
                acc[nt][0] = __builtin_amdgcn_mfma_f32_16x16x32_bf16(W2A[nt][s], x0, acc[nt][0], 0, 0, 0);
                acc[nt][1] = __builtin_amdgcn_mfma_f32_16x16x32_bf16(W2A[nt][s], x1, acc[nt][1], 0, 0, 0);
            }
        }
#pragma unroll
        for (int nt = 0; nt < 2; ++nt)
#pragma unroll
            for (int ct = 0; ct < 2; ++ct) {
                sv4 pk;
                pk[0] = f2bf(fmaxf(acc[nt][ct][0] + bias2[nt].x, 0.f));
                pk[1] = f2bf(fmaxf(acc[nt][ct][1] + bias2[nt].y, 0.f));
                pk[2] = f2bf(fmaxf(acc[nt][ct][2] + bias2[nt].z, 0.f));
                pk[3] = f2bf(fmaxf(acc[nt][ct][3] + bias2[nt].w, 0.f));
                *(sv4*)&sH[1][ct * 16 + ln][w * 32 + nt * 16 + q * 4] = pk;
            }
        __syncthreads();

        // ---- GEMM3 (K-split: wave w takes k in [32w,32w+32)) + LDS-atomic segsum ----
        {
            floatx4 a3[2];
            a3[0] = (floatx4){0.f, 0.f, 0.f, 0.f};
            a3[1] = (floatx4){0.f, 0.f, 0.f, 0.f};
            short8 x0 = *(const short8*)&sH[1][ln][w * 32 + q * 8];
            short8 x1 = *(const short8*)&sH[1][16 + ln][w * 32 + q * 8];
            a3[0] = __builtin_amdgcn_mfma_f32_16x16x32_bf16(W3A, x0, a3[0], 0, 0, 0);
            a3[1] = __builtin_amdgcn_mfma_f32_16x16x32_bf16(W3A, x1, a3[1], 0, 0, 0);
#pragma unroll
            for (int ct = 0; ct < 2; ++ct) {
                int seg = sSeg[ct * 16 + ln];
#pragma unroll
                for (int r = 0; r < 4; ++r)
                    atomicAdd(&lAcc[seg * D_OUT + q * 4 + r], a3[ct][r]);
            }
        }
        __syncthreads();   // protect sXp/sSeg/sH before next tile's staging
    }

    // ---- write deterministic block partials ----
    float* dst = part + (size_t)blockIdx.x * PART_STRIDE;
    for (int i = tid; i < B_SAMP * D_OUT; i += 512) dst[i] = lAcc[i];
    if (tid < B_SAMP) dst[B_SAMP * D_OUT + tid] = lCnt[tid];
}

__global__ __launch_bounds__(256)
void finalize(const float* __restrict__ part, const float* __restrict__ b3,
              float* __restrict__ out) {
    int o = blockIdx.x * blockDim.x + threadIdx.x;   // 0..8191
    int s = o >> 4;
    float sum = 0.f, cnt = 0.f;
#pragma unroll 8
    for (int c = 0; c < GRID; ++c) {
        sum += part[(size_t)c * PART_STRIDE + o];
        cnt += part[(size_t)c * PART_STRIDE + B_SAMP * D_OUT + s];
    }
    out[o] = (cnt > 0.f) ? (sum / cnt + b3[o & 15]) : 0.f;
}

extern "C" void kernel_launch(void* const* d_in, const int* in_sizes, int n_in,
                              void* d_out, int out_size, void* d_ws, size_t ws_size,
                              hipStream_t stream) {
    const float* X   = (const float*)d_in[0];
    const float* Z   = (const float*)d_in[1];
    const float* W1  = (const float*)d_in[2];
    const float* b1  = (const float*)d_in[3];
    const float* W2  = (const float*)d_in[4];
    const float* b2  = (const float*)d_in[5];
    const float* W3  = (const float*)d_in[6];
    const float* b3  = (const float*)d_in[7];
    const int*   c2b = (const int*)d_in[8];
    const int*   sidx= (const int*)d_in[9];

    char* ws = (char*)d_ws;
    __hip_bfloat16* w1p = (__hip_bfloat16*)(ws + OFF_W1P);
    __hip_bfloat16* w2p = (__hip_bfloat16*)(ws + OFF_W2P);
    __hip_bfloat16* w3p = (__hip_bfloat16*)(ws + OFF_W3P);
    float* part = (float*)(ws + OFF_PART);
    float* out  = (float*)d_out;

    pack_w<<<160, 256, 0, stream>>>(W1, w1p, H_DIM, 5);
    pack_w<<<256, 256, 0, stream>>>(W2, w2p, H_DIM, 8);
    pack_w<<<16,  256, 0, stream>>>(W3, w3p, D_OUT, 8);

    fused_persist<<<GRID, 512, 0, stream>>>(X, Z, c2b, sidx, b1, b2,
                                            w1p, w2p, w3p, part);
    finalize<<<32, 256, 0, stream>>>(part, b3, out);
}